// Round 7
// baseline (243.795 us; speedup 1.0000x reference)
//
#include <hip/hip_runtime.h>
#include <hip/hip_cooperative_groups.h>

namespace cg = cooperative_groups;

// 20-qubit feature map, 4 layers (RX·RY per wire + CNOT chain), <Z_i> outputs.
// wire w <-> bit (19-w). CNOT chain == gray perm: new[y] = old[y ^ (y>>1)], folded
// into the next A-phase read / final expectation. Layer 1 on |0..0> = product state.
// R7: ONE cooperative kernel; R4's verified phase bodies verbatim; kernel
// boundaries -> grid.sync(); gates computed per-block in LDS; reduce in block 0.

#define NW 20

__device__ __forceinline__ float2 cmul(float2 a, float2 b) {
    return make_float2(a.x*b.x - a.y*b.y, a.x*b.y + a.y*b.x);
}

__device__ __forceinline__ void apply_gate(float2& a0, float2& a1,
                                           float2 u00, float2 u01,
                                           float2 u10, float2 u11) {
    float2 b0, b1;
    b0.x = u00.x*a0.x - u00.y*a0.y + u01.x*a1.x - u01.y*a1.y;
    b0.y = u00.x*a0.y + u00.y*a0.x + u01.x*a1.y + u01.y*a1.x;
    b1.x = u10.x*a0.x - u10.y*a0.y + u11.x*a1.x - u11.y*a1.y;
    b1.y = u10.x*a0.y + u10.y*a0.x + u11.x*a1.y + u11.y*a1.x;
    a0 = b0; a1 = b1;
}

__device__ __forceinline__ float2 shflx(float2 v, int m) {
    float2 r;
    r.x = __shfl_xor(v.x, m, 64);
    r.y = __shfl_xor(v.y, m, 64);
    return r;
}

template<int A>
__device__ __forceinline__ void gate_regbit(float2 (&amp)[8], const float2* Gw) {
    float2 u00 = Gw[0], u01 = Gw[1], u10 = Gw[2], u11 = Gw[3];
    #pragma unroll
    for (int r = 0; r < 8; r++)
        if (!(r & (1 << A)))
            apply_gate(amp[r], amp[r | (1 << A)], u00, u01, u10, u11);
}

// butterfly: swap reg-bit A with lane bit LM (R4-verified orientation)
template<int A, int LM>
__device__ __forceinline__ void swap_reg_lane(float2 (&amp)[8], unsigned lane) {
    bool hb = (lane & (unsigned)LM) != 0u;
    #pragma unroll
    for (int r = 0; r < 8; r++) {
        if (!(r & (1 << A))) {
            float2 lo = amp[r], hi = amp[r | (1 << A)];
            float2 xs = hb ? lo : hi;
            float2 ys = shflx(xs, LM);
            amp[r]            = hb ? ys : lo;
            amp[r | (1 << A)] = hb ? hi : ys;
        }
    }
}

// ---- Phase A (R4 stageA body, verbatim maps): gates on bits 0..11, block = H ----
template<int MODE>
__device__ void phaseA(float2* lds, const float2* src, float2* dst, const float2* G) {
    const unsigned t = threadIdx.x;
    const unsigned lane = t & 63u, wv = t >> 6;
    const unsigned H   = blockIdx.x;
    const unsigned Hp  = H ^ (H >> 1);
    const unsigned inj = (H & 1u) << 11;
    const unsigned lb  = (wv << 9) | (lane << 3);
    const unsigned gb  = (lb ^ (lb >> 1)) ^ inj;

    float2 amp[8];
    if (MODE == 1) {
        const float4* q = (const float4*)(src + ((size_t)Hp << 12) + (gb & ~7u));
        float4 q0 = q[0], q1 = q[1], q2 = q[2], q3 = q[3];
        float2 e0 = make_float2(q0.x,q0.y), e1 = make_float2(q0.z,q0.w);
        float2 e2 = make_float2(q1.x,q1.y), e3 = make_float2(q1.z,q1.w);
        float2 e4 = make_float2(q2.x,q2.y), e5 = make_float2(q2.z,q2.w);
        float2 e6 = make_float2(q3.x,q3.y), e7 = make_float2(q3.z,q3.w);
        bool f = (gb & 4u) != 0u;
        amp[0] = f ? e4 : e0;  amp[1] = f ? e5 : e1;
        amp[2] = f ? e7 : e3;  amp[3] = f ? e6 : e2;
        amp[4] = f ? e2 : e6;  amp[5] = f ? e3 : e7;
        amp[6] = f ? e1 : e5;  amp[7] = f ? e0 : e4;
    } else {
        float2 P = make_float2(1.0f, 0.0f);
        #pragma unroll
        for (int b = 12; b <= 19; b++)
            P = cmul(P, G[(19-b)*4 + (int)((Hp >> (b-12)) & 1u)*2]);
        #pragma unroll
        for (int b = 3; b <= 11; b++)
            P = cmul(P, G[(19-b)*4 + (int)((gb >> b) & 1u)*2]);
        float2 Tt[8];
        #pragma unroll
        for (int j = 0; j < 8; j++) {
            float2 v = cmul(G[18*4 + ((j>>1)&1)*2], G[19*4 + (j&1)*2]);
            v = cmul(G[17*4 + ((j>>2)&1)*2], v);
            Tt[j] = cmul(P, v);
        }
        bool f = (gb & 4u) != 0u;
        amp[0] = f ? Tt[4] : Tt[0];  amp[1] = f ? Tt[5] : Tt[1];
        amp[2] = f ? Tt[7] : Tt[3];  amp[3] = f ? Tt[6] : Tt[2];
        amp[4] = f ? Tt[2] : Tt[6];  amp[5] = f ? Tt[3] : Tt[7];
        amp[6] = f ? Tt[1] : Tt[5];  amp[7] = f ? Tt[0] : Tt[4];
    }

    gate_regbit<0>(amp, G + 19*4);
    gate_regbit<1>(amp, G + 18*4);
    gate_regbit<2>(amp, G + 17*4);
    swap_reg_lane<0,1>(amp, lane);
    swap_reg_lane<1,2>(amp, lane);
    swap_reg_lane<2,4>(amp, lane);
    gate_regbit<0>(amp, G + 16*4);
    gate_regbit<1>(amp, G + 15*4);
    gate_regbit<2>(amp, G + 14*4);
    swap_reg_lane<0,8>(amp, lane);
    swap_reg_lane<1,16>(amp, lane);
    swap_reg_lane<2,32>(amp, lane);
    gate_regbit<0>(amp, G + 13*4);
    gate_regbit<1>(amp, G + 12*4);
    gate_regbit<2>(amp, G + 11*4);
    #pragma unroll
    for (int k = 0; k < 8; k++) lds[(wv << 9) | ((unsigned)k << 6) | lane] = amp[k];
    __syncthreads();
    #pragma unroll
    for (int k = 0; k < 8; k++) amp[k] = lds[((unsigned)k << 9) | (wv << 6) | lane];
    __syncthreads();                      // lds reused next phase
    gate_regbit<0>(amp, G + 10*4);
    gate_regbit<1>(amp, G +  9*4);
    gate_regbit<2>(amp, G +  8*4);
    float2* d = dst + ((size_t)H << 12);
    #pragma unroll
    for (int k = 0; k < 8; k++) d[((unsigned)k << 9) | (wv << 6) | lane] = amp[k];
}

// ---- Phase B (R4 stageB body, verbatim maps): gates on bits 12..19, block = bb ----
template<int FUSE>
__device__ void phaseB(float2* lds, float2* st, const float2* G, float* partial) {
    const unsigned t = threadIdx.x, lane = t & 63u, wv = t >> 6;
    const unsigned bb = blockIdx.x;
    const unsigned m = lane & 15u, l45 = lane >> 4;

    float2 amp[8];
    #pragma unroll
    for (int k = 0; k < 8; k++) {
        unsigned h = (unsigned)k | (l45 << 3) | (wv << 5);
        amp[k] = st[((size_t)h << 12) | (bb << 4) | m];
    }
    gate_regbit<0>(amp, G + 7*4);
    gate_regbit<1>(amp, G + 6*4);
    gate_regbit<2>(amp, G + 5*4);
    swap_reg_lane<0,16>(amp, lane);
    swap_reg_lane<1,32>(amp, lane);
    gate_regbit<0>(amp, G + 4*4);
    gate_regbit<1>(amp, G + 3*4);
    #pragma unroll
    for (int k = 0; k < 8; k++) {
        unsigned li = lane | ((((unsigned)k >> 2) & 1u) << 6) | (((unsigned)k & 1u) << 7)
                    | ((((unsigned)k >> 1) & 1u) << 8) | (wv << 9);
        lds[li] = amp[k];
    }
    __syncthreads();
    #pragma unroll
    for (int k = 0; k < 8; k++) amp[k] = lds[lane | (wv << 6) | ((unsigned)k << 9)];
    __syncthreads();                      // lds reused (next phase / reduction)
    gate_regbit<0>(amp, G + 2*4);
    gate_regbit<1>(amp, G + 1*4);
    gate_regbit<2>(amp, G + 0*4);

    if (!FUSE) {
        #pragma unroll
        for (int k = 0; k < 8; k++) {
            unsigned h = l45 | (wv << 2) | ((unsigned)k << 5);
            st[((size_t)h << 12) | (bb << 4) | m] = amp[k];
        }
    } else {
        float p[8];
        #pragma unroll
        for (int k = 0; k < 8; k++) p[k] = amp[k].x*amp[k].x + amp[k].y*amp[k].y;
        float Se = p[0]+p[3]+p[5]+p[6];
        float So = p[1]+p[2]+p[4]+p[7];
        float D  = Se - So;
        float S0 = (p[0]+p[1]+p[2]+p[3]) - (p[4]+p[5]+p[6]+p[7]);
        float S1 = (p[0]+p[1]+p[6]+p[7]) - (p[2]+p[3]+p[4]+p[5]);
        unsigned hlow = l45 | (wv << 2);
        unsigned v = (hlow << 12) | (bb << 4) | m;
        unsigned cm = v; cm ^= cm >> 1; cm ^= cm >> 2; cm ^= cm >> 4;
        cm ^= cm >> 8; cm ^= cm >> 16;
        float acc[NW];
        acc[0] = S0; acc[1] = S1; acc[2] = D;
        #pragma unroll
        for (int w = 3; w < NW; w++)
            acc[w] = ((cm >> (19 - w)) & 1u) ? -D : D;

        float* red = (float*)lds;
        #pragma unroll
        for (int w = 0; w < NW; w++) {
            float s = acc[w];
            #pragma unroll
            for (int off = 32; off; off >>= 1) s += __shfl_down(s, off, 64);
            if (lane == 0) red[wv*NW + w] = s;
        }
        __syncthreads();
        if (t < NW) {
            float s = 0.0f;
            #pragma unroll
            for (int w8 = 0; w8 < 8; w8++) s += red[w8*NW + (int)t];
            partial[bb*NW + t] = s;
        }
    }
}

// ---- single cooperative kernel ----
__global__ __launch_bounds__(512) void qfm_all(const float* __restrict__ x,
                                               float2* __restrict__ buf0,
                                               float2* __restrict__ buf1,
                                               float* __restrict__ partial,
                                               float* __restrict__ out) {
    __shared__ float2 lds[4096];
    __shared__ float2 Gs[4*NW];
    const unsigned t = threadIdx.x;

    // per-block gate prep: U = RY(x)*RX(x), half-angle
    if (t < NW) {
        float h = 0.5f * x[t];
        float c = cosf(h), s = sinf(h);
        float cc = c*c, ss = s*s, cs = c*s;
        Gs[t*4+0] = make_float2(cc,  ss);
        Gs[t*4+1] = make_float2(-cs, -cs);
        Gs[t*4+2] = make_float2(cs,  -cs);
        Gs[t*4+3] = make_float2(cc,  -ss);
    }
    __syncthreads();

    cg::grid_group grid = cg::this_grid();

    phaseA<0>(lds, buf1, buf0, Gs);       // L1 (product) + L2 b0..11
    grid.sync();
    phaseB<0>(lds, buf0, Gs, nullptr);    // L2 b12..19
    grid.sync();
    phaseA<1>(lds, buf0, buf1, Gs);       // perm fold + L3 b0..11
    grid.sync();
    phaseB<0>(lds, buf1, Gs, nullptr);    // L3 b12..19
    grid.sync();
    phaseA<1>(lds, buf1, buf0, Gs);       // perm fold + L4 b0..11
    grid.sync();
    phaseB<1>(lds, buf0, Gs, partial);    // L4 b12..19 + expectation partials
    grid.sync();

    if (blockIdx.x == 0) {
        // reduce 256x20 partials; all 512 threads participate (uniform barriers)
        float vals[NW];
        #pragma unroll
        for (int w = 0; w < NW; w++)
            vals[w] = (t < 256u) ? partial[t*NW + w] : 0.0f;
        float* red = (float*)lds;
        const unsigned lane = t & 63u, wv = t >> 6;
        #pragma unroll
        for (int w = 0; w < NW; w++) {
            float v = vals[w];
            #pragma unroll
            for (int off = 32; off; off >>= 1) v += __shfl_down(v, off, 64);
            if (lane == 0) red[wv*NW + w] = v;
        }
        __syncthreads();
        if (t < NW) {
            float s = 0.0f;
            #pragma unroll
            for (int w8 = 0; w8 < 8; w8++) s += red[w8*NW + (int)t];
            out[t] = s;
        }
    }
}

extern "C" void kernel_launch(void* const* d_in, const int* in_sizes, int n_in,
                              void* d_out, int out_size, void* d_ws, size_t ws_size,
                              hipStream_t stream) {
    (void)in_sizes; (void)n_in; (void)out_size; (void)ws_size;
    const float* x = (const float*)d_in[0];
    float* out = (float*)d_out;

    char* ws = (char*)d_ws;
    float*  partial = (float*)(ws + 1024);                        // 20 KB
    float2* buf0    = (float2*)(ws + 65536);                      // 8 MB
    float2* buf1    = (float2*)(ws + 65536 + (size_t)(8u << 20)); // 8 MB

    void* args[] = { (void*)&x, (void*)&buf0, (void*)&buf1, (void*)&partial, (void*)&out };
    hipLaunchCooperativeKernel((const void*)qfm_all, dim3(256), dim3(512),
                               args, 0, stream);
}

// Round 8
// 63.711 us; speedup vs baseline: 3.8266x; 3.8266x over previous
//
#include <hip/hip_runtime.h>

// 20-qubit feature map, 4 layers (RX·RY per wire + CNOT chain), <Z_i> outputs.
// wire w <-> bit (19-w). CNOT chain == gray perm: new[y] = old[y ^ (y>>1)], folded
// into the next A read (MODE1) or final expectation (FUSE). Layer 1 on |0..0> is a
// product state computed in-register (MODE0).
// R8: R4's 6-pass dispatch structure (dispatch = the cheap cross-XCD barrier; R7
// proved grid.sync costs ~29 us each). Engine: 1024 thr/block x 4 amps/thread
// -> 16 waves/CU (2x R4's TLP). A: regs=b0,b1 walk up via butterflies + 2 LDS
// trips; B: same on bits 12..19. Gates prepped per-block in LDS (no prep kernel).

#define NW 20

__device__ __forceinline__ float2 cmul(float2 a, float2 b) {
    return make_float2(a.x*b.x - a.y*b.y, a.x*b.y + a.y*b.x);
}

__device__ __forceinline__ void apply_gate(float2& a0, float2& a1,
                                           float2 u00, float2 u01,
                                           float2 u10, float2 u11) {
    float2 b0, b1;
    b0.x = u00.x*a0.x - u00.y*a0.y + u01.x*a1.x - u01.y*a1.y;
    b0.y = u00.x*a0.y + u00.y*a0.x + u01.x*a1.y + u01.y*a1.x;
    b1.x = u10.x*a0.x - u10.y*a0.y + u11.x*a1.x - u11.y*a1.y;
    b1.y = u10.x*a0.y + u10.y*a0.x + u11.x*a1.y + u11.y*a1.x;
    a0 = b0; a1 = b1;
}

__device__ __forceinline__ float2 shflx(float2 v, int m) {
    float2 r;
    r.x = __shfl_xor(v.x, m, 64);
    r.y = __shfl_xor(v.y, m, 64);
    return r;
}

// suffix-XOR: bit b of result = XOR_{j>=b} x_j
__device__ __forceinline__ unsigned sfx(unsigned x) {
    x ^= x >> 1; x ^= x >> 2; x ^= x >> 4; x ^= x >> 8; x ^= x >> 16; return x;
}

// plain gate pairing reg-bit A (4-amp variant of the R4-verified engine)
template<int A>
__device__ __forceinline__ void gate_regbit4(float2 (&amp)[4], const float2* Gw) {
    float2 u00 = Gw[0], u01 = Gw[1], u10 = Gw[2], u11 = Gw[3];
    #pragma unroll
    for (int r = 0; r < 4; r++)
        if (!(r & (1 << A)))
            apply_gate(amp[r], amp[r | (1 << A)], u00, u01, u10, u11);
}

// butterfly: swap reg-bit A with lane bit LM (R4-verified orientation)
template<int A, int LM>
__device__ __forceinline__ void swap_reg_lane4(float2 (&amp)[4], unsigned lane) {
    bool hb = (lane & (unsigned)LM) != 0u;
    #pragma unroll
    for (int r = 0; r < 4; r++) {
        if (!(r & (1 << A))) {
            float2 lo = amp[r], hi = amp[r | (1 << A)];
            float2 xs = hb ? lo : hi;
            float2 ys = shflx(xs, LM);
            amp[r]            = hb ? ys : lo;
            amp[r | (1 << A)] = hb ? hi : ys;
        }
    }
}

// per-block gate prep: U = RY(x)*RX(x), half-angle h = x/2
__device__ __forceinline__ void prep_Gs(const float* __restrict__ x, float2* Gs,
                                        unsigned t) {
    if (t < NW) {
        float h = 0.5f * x[t];
        float c = cosf(h), s = sinf(h);
        float cc = c*c, ss = s*s, cs = c*s;
        Gs[t*4+0] = make_float2(cc,  ss);
        Gs[t*4+1] = make_float2(-cs, -cs);
        Gs[t*4+2] = make_float2(cs,  -cs);
        Gs[t*4+3] = make_float2(cc,  -ss);
    }
}

// Stage A: gates on bits 0..11 (wires 19..8). Block = logical high byte H.
// Thread: regs = 2 bits (walking), lanes l0..5, waves w0..3. 4 amps/thread.
// MODE 0: product state (layer-1 folded). MODE 1: gray-fold read from src.
template<int MODE>
__global__ __launch_bounds__(1024) void stageA(const float* __restrict__ x,
                                               const float2* __restrict__ src,
                                               float2* __restrict__ dst) {
    __shared__ float2 lds[4096];
    __shared__ float2 Gs[4*NW];
    const unsigned t = threadIdx.x;
    prep_Gs(x, Gs, t);
    __syncthreads();
    const unsigned lane = t & 63u, wv = t >> 6;           // wv: 4 bits
    const unsigned w0 = wv & 1u, w1 = (wv >> 1) & 1u, w2 = (wv >> 2) & 1u, w3 = wv >> 3;
    const unsigned H   = blockIdx.x;
    const unsigned Hp  = H ^ (H >> 1);
    const unsigned inj = (H & 1u) << 11;
    const unsigned lb  = (wv << 8) | (lane << 2);         // logical low-12 base
    const unsigned gb  = (lb ^ (lb >> 1)) ^ inj;          // gray12 ^ inj; gb&3 in {0,2}

    float2 amp[4];
    if (MODE == 1) {
        // phys low-12 = gb ^ gray2(k); aligned 32B quad at gb&~3
        const float4* q = (const float4*)(src + ((size_t)Hp << 12) + (gb & ~3u));
        float4 q0 = q[0], q1 = q[1];
        float2 e0 = make_float2(q0.x,q0.y), e1 = make_float2(q0.z,q0.w);
        float2 e2 = make_float2(q1.x,q1.y), e3 = make_float2(q1.z,q1.w);
        bool s2 = (gb & 2u) != 0u;   // amp[k] = e[(gb&3) ^ gray2(k)], gray2: 0,1,3,2
        amp[0] = s2 ? e2 : e0;
        amp[1] = s2 ? e3 : e1;
        amp[2] = s2 ? e1 : e3;
        amp[3] = s2 ? e0 : e2;
    } else {
        // amp(Y) = prod_b U^{19-b}[z_b][0], z = gray20(Y)
        float2 P = make_float2(1.0f, 0.0f);
        #pragma unroll
        for (int b = 12; b <= 19; b++)
            P = cmul(P, Gs[(19-b)*4 + (int)((Hp >> (b-12)) & 1u)*2]);
        #pragma unroll
        for (int b = 2; b <= 11; b++)
            P = cmul(P, Gs[(19-b)*4 + (int)((gb >> b) & 1u)*2]);
        float2 T[4];
        #pragma unroll
        for (int j = 0; j < 4; j++)
            T[j] = cmul(P, cmul(Gs[19*4 + (j&1)*2], Gs[18*4 + ((j>>1)&1)*2]));
        bool s2 = (gb & 2u) != 0u;
        amp[0] = s2 ? T[2] : T[0];
        amp[1] = s2 ? T[3] : T[1];
        amp[2] = s2 ? T[1] : T[3];
        amp[3] = s2 ? T[0] : T[2];
    }

    gate_regbit4<0>(amp, Gs + 19*4);   // b0
    gate_regbit4<1>(amp, Gs + 18*4);   // b1
    swap_reg_lane4<0,1>(amp, lane);    // b0<->b2
    swap_reg_lane4<1,2>(amp, lane);    // b1<->b3
    gate_regbit4<0>(amp, Gs + 17*4);   // b2
    gate_regbit4<1>(amp, Gs + 16*4);   // b3
    swap_reg_lane4<0,4>(amp, lane);
    swap_reg_lane4<1,8>(amp, lane);
    gate_regbit4<0>(amp, Gs + 15*4);   // b4
    gate_regbit4<1>(amp, Gs + 14*4);   // b5
    swap_reg_lane4<0,16>(amp, lane);
    swap_reg_lane4<1,32>(amp, lane);
    gate_regbit4<0>(amp, Gs + 13*4);   // b6
    gate_regbit4<1>(amp, Gs + 12*4);   // b7
    // map: l=b0..5, regs={b6,b7}, wv=b8..11
    // X1: a0..5=b0..5, a6,a7=b6,b7, a8..11=b8..11
    #pragma unroll
    for (int k = 0; k < 4; k++) lds[lane | ((unsigned)k << 6) | (wv << 8)] = amp[k];
    __syncthreads();
    // read: regs={b8,b9}; w0,w1 keep b6,b7; w2,w3 = b10,b11
    #pragma unroll
    for (int k = 0; k < 4; k++)
        amp[k] = lds[lane | (w0 << 6) | (w1 << 7) | ((unsigned)k << 8) | (w2 << 10) | (w3 << 11)];
    gate_regbit4<0>(amp, Gs + 11*4);   // b8
    gate_regbit4<1>(amp, Gs + 10*4);   // b9
    __syncthreads();
    // X2: a6,a7=b8,b9 ; a8,a9=b6,b7 ; a10,a11=b10,b11
    #pragma unroll
    for (int k = 0; k < 4; k++) lds[lane | ((unsigned)k << 6) | (wv << 8)] = amp[k];
    __syncthreads();
    // read: regs={b10,b11}; w0,w1 keep b6,b7 (a8,a9); w2,w3 = b8,b9 (a6,a7)
    #pragma unroll
    for (int k = 0; k < 4; k++)
        amp[k] = lds[lane | (w2 << 6) | (w3 << 7) | (w0 << 8) | (w1 << 9) | ((unsigned)k << 10)];
    gate_regbit4<0>(amp, Gs + 9*4);    // b10
    gate_regbit4<1>(amp, Gs + 8*4);    // b11
    // store logical: Y = lane | b6,b7(w0,w1) | b8,b9(w2,w3) | b10,b11(k)
    float2* d = dst + ((size_t)H << 12);
    #pragma unroll
    for (int k = 0; k < 4; k++)
        d[lane | (w0 << 6) | (w1 << 7) | (w2 << 8) | (w3 << 9) | ((unsigned)k << 10)] = amp[k];
}

// Stage B: gates on bits 12..19 (wires 7..0), h = bits 12..19; in-place;
// block = bits 4..11 (bb); m = lane&15 = bits 0..3 (128B runs).
// FUSE=1: final layer -> fold last gray perm, accumulate <Z_w> partials.
template<int FUSE>
__global__ __launch_bounds__(1024) void stageB(const float* __restrict__ x,
                                               float2* __restrict__ st,
                                               float* __restrict__ partial) {
    __shared__ float2 lds[4096];
    __shared__ float2 Gs[4*NW];
    const unsigned t = threadIdx.x;
    prep_Gs(x, Gs, t);
    __syncthreads();
    const unsigned lane = t & 63u, wv = t >> 6;
    const unsigned w0 = wv & 1u, w1 = (wv >> 1) & 1u, w2 = (wv >> 2) & 1u, w3 = wv >> 3;
    const unsigned bb = blockIdx.x;
    const unsigned m = lane & 15u, l4 = (lane >> 4) & 1u, l5 = lane >> 5;

    // load: h = k(h0,h1) | l4(h2) | l5(h3) | wv(h4..7)
    float2 amp[4];
    #pragma unroll
    for (int k = 0; k < 4; k++) {
        unsigned h = (unsigned)k | (l4 << 2) | (l5 << 3) | (wv << 4);
        amp[k] = st[((size_t)h << 12) | (bb << 4) | m];
    }
    gate_regbit4<0>(amp, Gs + 7*4);    // h0 (b12, wire 7)
    gate_regbit4<1>(amp, Gs + 6*4);    // h1 (b13)
    swap_reg_lane4<0,16>(amp, lane);   // h0<->h2
    swap_reg_lane4<1,32>(amp, lane);   // h1<->h3
    gate_regbit4<0>(amp, Gs + 5*4);    // h2 (b14)
    gate_regbit4<1>(amp, Gs + 4*4);    // h3 (b15)
    // map: l4=h0, l5=h1, regs={h2,h3}, wv=h4..7
    // X1: a0..3=m, a4=h0, a5=h1, a6,a7=h2,h3, a8..11=h4..7
    #pragma unroll
    for (int k = 0; k < 4; k++) lds[lane | ((unsigned)k << 6) | (wv << 8)] = amp[k];
    __syncthreads();
    // read: regs={h4,h5}; w0,w1 = h2,h3; w2,w3 = h6,h7
    #pragma unroll
    for (int k = 0; k < 4; k++)
        amp[k] = lds[lane | (w0 << 6) | (w1 << 7) | ((unsigned)k << 8) | (w2 << 10) | (w3 << 11)];
    gate_regbit4<0>(amp, Gs + 3*4);    // h4 (b16)
    gate_regbit4<1>(amp, Gs + 2*4);    // h5 (b17)
    __syncthreads();
    // X2: a6,a7=h4,h5 ; a8,a9=h2,h3 ; a10,a11=h6,h7
    #pragma unroll
    for (int k = 0; k < 4; k++) lds[lane | ((unsigned)k << 6) | (wv << 8)] = amp[k];
    __syncthreads();
    // read: regs={h6,h7}; w0,w1 keep h2,h3 (a8,a9); w2,w3 = h4,h5 (a6,a7)
    #pragma unroll
    for (int k = 0; k < 4; k++)
        amp[k] = lds[lane | (w2 << 6) | (w3 << 7) | (w0 << 8) | (w1 << 9) | ((unsigned)k << 10)];
    gate_regbit4<0>(amp, Gs + 1*4);    // h6 (b18)
    gate_regbit4<1>(amp, Gs + 0*4);    // h7 (b19)
    // final map: l4=h0, l5=h1, w0=h2, w1=h3, w2=h4, w3=h5, k={h6,h7}

    if (!FUSE) {
        #pragma unroll
        for (int k = 0; k < 4; k++) {
            unsigned h = l4 | (l5 << 1) | (w0 << 2) | (w1 << 3) | (w2 << 4) | (w3 << 5)
                       | (((unsigned)k & 1u) << 6) | (((unsigned)k >> 1) << 7);
            st[((size_t)h << 12) | (bb << 4) | m] = amp[k];
        }
    } else {
        // y = invgray(Y); k0 = Y18, k1 = Y19.
        float p[4];
        #pragma unroll
        for (int k = 0; k < 4; k++) p[k] = amp[k].x*amp[k].x + amp[k].y*amp[k].y;
        float S19 = (p[0] + p[1]) - (p[2] + p[3]);      // (-1)^{Y19}
        float D   = p[0] - p[1] - p[2] + p[3];          // (-1)^{Y18^Y19}
        unsigned v = m | (bb << 4) | (l4 << 12) | (l5 << 13) | (w0 << 14)
                   | (w1 << 15) | (w2 << 16) | (w3 << 17);   // Y bits 0..17
        unsigned cm = sfx(v);                            // cm_b = XOR_{j=b..17} Y_j
        float acc[NW];
        acc[0] = S19; acc[1] = D;
        #pragma unroll
        for (int w = 2; w < NW; w++)
            acc[w] = ((cm >> (19 - w)) & 1u) ? -D : D;

        __syncthreads();                 // gate LDS reads done; reuse for reduction
        float* red = (float*)lds;
        #pragma unroll
        for (int w = 0; w < NW; w++) {
            float s = acc[w];
            #pragma unroll
            for (int off = 32; off; off >>= 1) s += __shfl_down(s, off, 64);
            if (lane == 0) red[wv*NW + w] = s;
        }
        __syncthreads();
        if (t < NW) {
            float s = 0.0f;
            #pragma unroll
            for (int v16 = 0; v16 < 16; v16++) s += red[v16*NW + (int)t];
            partial[bb*NW + t] = s;
        }
    }
}

__global__ __launch_bounds__(256) void reduce_out(const float* __restrict__ partial,
                                                  float* __restrict__ out) {
    __shared__ float red[4*NW];
    unsigned t = threadIdx.x;
    float vals[NW];
    #pragma unroll
    for (int w = 0; w < NW; w++) vals[w] = partial[t*NW + w];
    #pragma unroll
    for (int w = 0; w < NW; w++) {
        float v = vals[w];
        #pragma unroll
        for (int off = 32; off; off >>= 1) v += __shfl_down(v, off, 64);
        if ((t & 63u) == 0u) red[(t >> 6)*NW + w] = v;
    }
    __syncthreads();
    if (t < NW) out[t] = red[t] + red[NW+t] + red[2*NW+t] + red[3*NW+t];
}

extern "C" void kernel_launch(void* const* d_in, const int* in_sizes, int n_in,
                              void* d_out, int out_size, void* d_ws, size_t ws_size,
                              hipStream_t stream) {
    (void)in_sizes; (void)n_in; (void)out_size; (void)ws_size;
    const float* x = (const float*)d_in[0];
    float* out = (float*)d_out;

    char* ws = (char*)d_ws;
    float*  partial = (float*)(ws + 1024);                        // 20 KB
    float2* buf0    = (float2*)(ws + 65536);                      // 8 MB
    float2* buf1    = (float2*)(ws + 65536 + (size_t)(8u << 20)); // 8 MB

    // layer 1 folded into product state; layer 2:
    stageA<0><<<256, 1024, 0, stream>>>(x, buf1 /*unused*/, buf0);
    stageB<0><<<256, 1024, 0, stream>>>(x, buf0, nullptr);
    // layer 3 (perm folded into A read):
    stageA<1><<<256, 1024, 0, stream>>>(x, buf0, buf1);
    stageB<0><<<256, 1024, 0, stream>>>(x, buf1, nullptr);
    // layer 4 (+ fused expectation, final perm folded):
    stageA<1><<<256, 1024, 0, stream>>>(x, buf1, buf0);
    stageB<1><<<256, 1024, 0, stream>>>(x, buf0, partial);
    reduce_out<<<1, 256, 0, stream>>>(partial, out);
}